// Round 24
// baseline (177.081 us; speedup 1.0000x reference)
//
#include <hip/hip_runtime.h>

#define BB 16
#define NN 8192
#define DMODEL 256
#define DKK 64
#define DVV 64
#define NQQ 256
#define TOK 32
#define MARGIN 0.16f
#define CAPF 131072
#define FB 32

typedef __attribute__((ext_vector_type(8))) short bf16x8;
typedef __attribute__((ext_vector_type(4))) float f32x4;

__device__ __forceinline__ unsigned short hi_bf16(float v) {
  unsigned u = __float_as_uint(v);
  return (unsigned short)(((u + 0x7FFFu + ((u >> 16) & 1u)) & 0xFFFF0000u) >> 16);
}

// prep: qk = q @ w_ks (f32, for recheck), bf16 fragments qhf, MT = (w_fc @ w_vs)^T
__global__ __launch_bounds__(256) void prep_kernel(
    const float* __restrict__ q, const float* __restrict__ w_ks,
    const float* __restrict__ w_vs, const float* __restrict__ w_fc,
    float* __restrict__ qk, float* __restrict__ MT,
    unsigned short* __restrict__ qhf, unsigned* __restrict__ cnt) {
  __shared__ float sbuf[DKK];
  const int tid = threadIdx.x;
  const int blk = blockIdx.x;
  if (blk == 0 && tid < 64) cnt[tid] = 0u;
  if (blk < NQQ) {
    const int s = blk;
    if (tid < DKK) sbuf[tid] = q[s * DKK + tid];
    __syncthreads();
    float acc = 0.f;
#pragma unroll
    for (int k = 0; k < DKK; ++k) acc = fmaf(sbuf[k], w_ks[k * DMODEL + tid], acc);
    qk[s * DMODEL + tid] = acc;
    int d = tid;
    int kstep = d >> 5, kg = (d >> 3) & 3, jj = d & 7;
    int stile = s >> 4, s15 = s & 15;
    int e = (((kstep * 16 + stile) * 64) + (kg * 16 + s15)) * 8 + jj;
    qhf[e] = hi_bf16(acc);
  } else {
    const int dm = blk - NQQ;
    if (tid < DVV) sbuf[tid] = w_vs[tid * DMODEL + dm];
    __syncthreads();
    float acc = 0.f;
#pragma unroll
    for (int v = 0; v < DVV; ++v) acc = fmaf(w_fc[tid * DVV + v], sbuf[v], acc);
    MT[dm * DMODEL + tid] = acc;
  }
}

// one k-step: prefetch B for k+1, FENCE, then 8 MFMAs for k
#define KSTEP(kk, Bhc, Bhn, PRE)                                                        \
  {                                                                                     \
    if (PRE) {                                                                          \
      _Pragma("unroll")                                                                 \
      for (int j = 0; j < 4; ++j)                                                       \
        Bhn[j] = bh[(((kk) + 1) * 16 + w * 4 + j) * 64 + l];                            \
      __builtin_amdgcn_sched_barrier(0);                                                \
    }                                                                                   \
    _Pragma("unroll")                                                                   \
    for (int i = 0; i < 2; ++i) {                                                       \
      bf16x8 Ah = *(const bf16x8*)(&xs_h[(((kk) * 2 + i) * 64 + l) * 8]);               \
      _Pragma("unroll")                                                                 \
      for (int j = 0; j < 4; ++j)                                                       \
        acc[i][j] = __builtin_amdgcn_mfma_f32_16x16x32_bf16(Ah, Bhc[j], acc[i][j], 0, 0, 0); \
    }                                                                                   \
  }

// main (r18 verbatim — measured optimum 83 us): bf16 MFMA scores; lean argmax;
// flagged (band>=2) -> batched fullcheck; nontemporal one-hot; idx byte.
__global__ __launch_bounds__(256, 4) void score_kernel(
    const float* __restrict__ x, const unsigned short* __restrict__ qhf,
    float* __restrict__ hard, unsigned char* __restrict__ idxa,
    unsigned* __restrict__ cnt, unsigned* __restrict__ listF) {
  __shared__ unsigned short xs_h[8192];   // 16 KB
  __shared__ float rm1[4][TOK];
  __shared__ int   ri1[4][TOK];
  __shared__ int   rcnt[4][TOK];
  __shared__ float bm1[TOK];
  __shared__ int   idx_s[TOK];

  const int tid = threadIdx.x;
  const int w = tid >> 6;
  const int l = tid & 63;
  const int b = blockIdx.y;
  const int n0 = blockIdx.x * TOK;
  const float* xbase = x + ((size_t)b * NN + n0) * DMODEL;
  const float4* xb4 = (const float4*)xbase;

  // ---- stage x tile as bf16-hi fragments ----
  {
    const int tok = w * 8 + (l >> 3);
    const int r   = l & 7;
    const int kg  = r >> 1;
    const int j0  = (r & 1) * 4;
    const int i   = tok >> 4;
    const int t15 = tok & 15;
#pragma unroll
    for (int it = 0; it < 8; ++it) {
      int c4 = it * 8 + r;
      float4 v = xb4[tok * 64 + c4];
      int e = (((it * 2 + i) * 64) + (kg * 16 + t15)) * 8 + j0;
      ushort4 hh;
      hh.x = hi_bf16(v.x); hh.y = hi_bf16(v.y);
      hh.z = hi_bf16(v.z); hh.w = hi_bf16(v.w);
      *(ushort4*)(&xs_h[e]) = hh;
    }
  }

  const bf16x8* bh = (const bf16x8*)qhf;
  bf16x8 BhA[4], BhB[4];
#pragma unroll
  for (int j = 0; j < 4; ++j) BhA[j] = bh[(w * 4 + j) * 64 + l];
  __syncthreads();

  f32x4 acc[2][4];
#pragma unroll
  for (int i = 0; i < 2; ++i)
#pragma unroll
    for (int j = 0; j < 4; ++j) acc[i][j] = (f32x4){0.f, 0.f, 0.f, 0.f};

  KSTEP(0, BhA, BhB, true)
  KSTEP(1, BhB, BhA, true)
  KSTEP(2, BhA, BhB, true)
  KSTEP(3, BhB, BhA, true)
  KSTEP(4, BhA, BhB, true)
  KSTEP(5, BhB, BhA, true)
  KSTEP(6, BhA, BhB, true)
  KSTEP(7, BhB, BhA, false)

  const int s15 = l & 15, g4 = l >> 4;

  // ---- pass A: per-wave value-only max ----
#pragma unroll
  for (int i = 0; i < 2; ++i) {
#pragma unroll
    for (int rr = 0; rr < 4; ++rr) {
      float m = fmaxf(fmaxf(acc[i][0][rr], acc[i][1][rr]),
                      fmaxf(acc[i][2][rr], acc[i][3][rr]));
#pragma unroll
      for (int off = 1; off < 16; off <<= 1)
        m = fmaxf(m, __shfl_xor(m, off, 64));
      if (s15 == 0) rm1[w][i * 16 + g4 * 4 + rr] = m;
    }
  }
  __syncthreads();

  // ---- global max per token ----
  if (tid < TOK)
    bm1[tid] = fmaxf(fmaxf(rm1[0][tid], rm1[1][tid]),
                     fmaxf(rm1[2][tid], rm1[3][tid]));
  __syncthreads();

  // ---- pass B: first-index of gmax + band count ----
#pragma unroll
  for (int i = 0; i < 2; ++i) {
#pragma unroll
    for (int rr = 0; rr < 4; ++rr) {
      int t = i * 16 + g4 * 4 + rr;
      float gm = bm1[t];
      float thr = gm - MARGIN;
      int c = 0;
      int im = 1024;
#pragma unroll
      for (int j = 0; j < 4; ++j) {
        float v = acc[i][j][rr];
        c += (v >= thr) ? 1 : 0;
        int s = w * 64 + j * 16 + s15;
        if (v == gm && s < im) im = s;
      }
#pragma unroll
      for (int off = 1; off < 16; off <<= 1) {
        c += __shfl_xor(c, off, 64);
        int oim = __shfl_xor(im, off, 64);
        im = min(im, oim);
      }
      if (s15 == 0) { rcnt[w][t] = c; ri1[w][t] = im; }
    }
  }
  __syncthreads();

  // ---- final: i1 = min matching index; flag if band >= 2 ----
  if (tid < TOK) {
    int i1 = min(min(ri1[0][tid], ri1[1][tid]), min(ri1[2][tid], ri1[3][tid]));
    int band = rcnt[0][tid] + rcnt[1][tid] + rcnt[2][tid] + rcnt[3][tid];
    idx_s[tid] = i1;
    idxa[(size_t)b * NN + n0 + tid] = (unsigned char)i1;
    if (band >= 2) {
      unsigned pos = atomicAdd(cnt, 1u);
      if (pos < CAPF) listF[pos] = (unsigned)(b * NN + n0 + tid);
    }
  }
  __syncthreads();

  // ---- one-hot write: nontemporal ----
  f32x4* hbase = (f32x4*)(hard + ((size_t)b * NN + n0) * NQQ);
#pragma unroll
  for (int it = 0; it < 8; ++it) {
    int u = it * 256 + tid;
    int tk = u >> 6;
    int s0 = (u & 63) * 4;
    int tgt = idx_s[tk];
    f32x4 h;
    h[0] = (s0 + 0 == tgt) ? 1.f : 0.f;
    h[1] = (s0 + 1 == tgt) ? 1.f : 0.f;
    h[2] = (s0 + 2 == tgt) ? 1.f : 0.f;
    h[3] = (s0 + 3 == tgt) ? 1.f : 0.f;
    __builtin_nontemporal_store(h, &hbase[u]);
  }
}

// full recheck: FB=32 tokens per block-iter — one qk sweep amortized over 32
// tokens (halves qk L2 traffic vs FB=16). 64 KB LDS -> 2 blocks/CU (compute-dense).
__global__ __launch_bounds__(256) void fullcheck_kernel(
    const float* __restrict__ x, const float* __restrict__ qk,
    const unsigned* __restrict__ cnt, const unsigned* __restrict__ listF,
    float* __restrict__ hard, unsigned char* __restrict__ idxa) {
  __shared__ float xs[FB][DMODEL];   // 32 KB
  __shared__ float sco[FB][NQQ];     // 32 KB
  __shared__ int   toks[FB];
  const int tid = threadIdx.x;
  unsigned n = cnt[0]; if (n > (unsigned)CAPF) n = CAPF;
  int nb = ((int)n + FB - 1) / FB;
  for (int batch = blockIdx.x; batch < nb; batch += gridDim.x) {
    int base = batch * FB;
    if (tid < FB) {
      int ei = base + tid;
      if (ei >= (int)n) ei = base;     // pad: duplicate first entry (idempotent)
      toks[tid] = (int)listF[ei];
    }
    __syncthreads();
#pragma unroll
    for (int t = 0; t < FB; ++t) xs[t][tid] = x[(size_t)toks[t] * DMODEL + tid];
    __syncthreads();
    float accv[FB];
#pragma unroll
    for (int t = 0; t < FB; ++t) accv[t] = 0.f;
    const float4* qrow = (const float4*)(qk + (size_t)tid * DMODEL);
    for (int d4 = 0; d4 < 64; ++d4) {
      float4 qv = qrow[d4];
#pragma unroll
      for (int t = 0; t < FB; ++t) {
        float4 xv = *(const float4*)(&xs[t][d4 * 4]);
        accv[t] = fmaf(qv.x, xv.x, accv[t]);
        accv[t] = fmaf(qv.y, xv.y, accv[t]);
        accv[t] = fmaf(qv.z, xv.z, accv[t]);
        accv[t] = fmaf(qv.w, xv.w, accv[t]);
      }
    }
#pragma unroll
    for (int t = 0; t < FB; ++t) sco[t][tid] = accv[t];
    __syncthreads();
    {
      // 32 groups of 8 lanes (8-aligned): group g reduces token g's 256 scores
      int g = tid >> 3, j = tid & 7;
      float bv = -1e30f; int bs = 256;
#pragma unroll
      for (int k = 0; k < 32; ++k) {
        int s = j + k * 8;
        float v = sco[g][s];
        if (v > bv) { bv = v; bs = s; }
      }
#pragma unroll
      for (int off = 1; off < 8; off <<= 1) {
        float ov = __shfl_xor(bv, off, 64);
        int   os = __shfl_xor(bs, off, 64);
        if (ov > bv || (ov == bv && os < bs)) { bv = ov; bs = os; }
      }
      if (j == 0) {
        int tok = toks[g];
        int olds = (int)idxa[tok];
        if (bs != olds) {
          hard[(size_t)tok * NQQ + olds] = 0.f;
          hard[(size_t)tok * NQQ + bs] = 1.f;
          idxa[tok] = (unsigned char)bs;
        }
      }
    }
    __syncthreads();
  }
}

// reduce+out fused (r23 verbatim): ballot-compaction + 8-wide MLP batching.
__global__ __launch_bounds__(512) void reduce_kernel(
    const float* __restrict__ x, const unsigned char* __restrict__ idxa,
    const float* __restrict__ MT, float* __restrict__ out) {
  __shared__ unsigned char  idx_l[NN];
  __shared__ unsigned short list_l[NN];
  __shared__ float accs[2][16][DMODEL];
  __shared__ unsigned lcnt;
  const int tid = threadIdx.x;
  const int l   = tid & 63;
  const int b  = blockIdx.x >> 4;
  const int sg = blockIdx.x & 15;
  const int h  = tid >> 8;
  const int d  = tid & 255;

  uint4 myidx = ((const uint4*)(idxa + (size_t)b * NN))[tid];
  ((uint4*)idx_l)[tid] = myidx;
  float* af = &accs[0][0][0];
#pragma unroll
  for (int i = 0; i < 16; ++i) af[i * 512 + tid] = 0.f;
  if (tid == 0) lcnt = 0u;
  __syncthreads();

  // phase 1: ballot-compaction of matching token ids
  {
    unsigned base16 = (unsigned)tid * 16u;
    unsigned words[4] = {myidx.x, myidx.y, myidx.z, myidx.w};
    unsigned long long lanelo = (1ull << l) - 1ull;
#pragma unroll
    for (int wi = 0; wi < 4; ++wi)
#pragma unroll
      for (int j = 0; j < 4; ++j) {
        int s = (words[wi] >> (8 * j)) & 255;
        bool m = ((s >> 4) == sg);
        unsigned long long mask = __ballot(m);
        int cw = __popcll(mask);
        unsigned wbase = 0;
        if (l == 0 && cw) wbase = atomicAdd(&lcnt, (unsigned)cw);
        wbase = (unsigned)__shfl((int)wbase, 0, 64);
        if (m) {
          int pos = (int)wbase + __popcll(mask & lanelo);
          list_l[pos] = (unsigned short)(base16 + wi * 4 + j);
        }
      }
  }
  __syncthreads();

  // phase 2: accumulate matching rows (8-wide independent-load batching)
  const int cnt_ = (int)lcnt;
  const float* xb = x + (size_t)b * NN * DMODEL + d;
  float* myacc = &accs[h][0][0] + d;
  int start = (h * cnt_) >> 1;
  int end   = ((h + 1) * cnt_) >> 1;
  int i = start;
  for (; i + 8 <= end; i += 8) {
    int n0_ = list_l[i],     n1_ = list_l[i + 1];
    int n2_ = list_l[i + 2], n3_ = list_l[i + 3];
    int n4_ = list_l[i + 4], n5_ = list_l[i + 5];
    int n6_ = list_l[i + 6], n7_ = list_l[i + 7];
    float v0 = xb[(size_t)n0_ * DMODEL];
    float v1 = xb[(size_t)n1_ * DMODEL];
    float v2 = xb[(size_t)n2_ * DMODEL];
    float v3 = xb[(size_t)n3_ * DMODEL];
    float v4 = xb[(size_t)n4_ * DMODEL];
    float v5 = xb[(size_t)n5_ * DMODEL];
    float v6 = xb[(size_t)n6_ * DMODEL];
    float v7 = xb[(size_t)n7_ * DMODEL];
    myacc[(idx_l[n0_] & 15) * DMODEL] += v0;
    myacc[(idx_l[n1_] & 15) * DMODEL] += v1;
    myacc[(idx_l[n2_] & 15) * DMODEL] += v2;
    myacc[(idx_l[n3_] & 15) * DMODEL] += v3;
    myacc[(idx_l[n4_] & 15) * DMODEL] += v4;
    myacc[(idx_l[n5_] & 15) * DMODEL] += v5;
    myacc[(idx_l[n6_] & 15) * DMODEL] += v6;
    myacc[(idx_l[n7_] & 15) * DMODEL] += v7;
  }
  for (; i < end; ++i) {
    int nn = list_l[i];
    myacc[(idx_l[nn] & 15) * DMODEL] += xb[(size_t)nn * DMODEL];
  }
  __syncthreads();

  // combine halves: accs[0] += accs[1]
#pragma unroll
  for (int ii = 0; ii < 8; ++ii) {
    int u = ii * 512 + tid;
    accs[0][u >> 8][u & 255] += accs[1][u >> 8][u & 255];
  }
  __syncthreads();

  // fused out: rows ss = h*8 .. h*8+7 of this slot-group
  float a[8];
#pragma unroll
  for (int i2 = 0; i2 < 8; ++i2) a[i2] = 0.f;
  for (int dm = 0; dm < DMODEL; ++dm) {
    float m = MT[(size_t)dm * DMODEL + d];
#pragma unroll
    for (int i2 = 0; i2 < 8; ++i2)
      a[i2] = fmaf(accs[0][h * 8 + i2][dm], m, a[i2]);
  }
  float* ob = out + ((size_t)b * NQQ + sg * 16 + h * 8) * DMODEL + d;
#pragma unroll
  for (int i2 = 0; i2 < 8; ++i2) ob[(size_t)i2 * DMODEL] = a[i2];
}

extern "C" void kernel_launch(void* const* d_in, const int* in_sizes, int n_in,
                              void* d_out, int out_size, void* d_ws, size_t ws_size,
                              hipStream_t stream) {
  const float* x   = (const float*)d_in[0];
  const float* q   = (const float*)d_in[1];
  const float* wks = (const float*)d_in[2];
  const float* wvs = (const float*)d_in[3];
  const float* wfc = (const float*)d_in[4];

  float* out  = (float*)d_out;                       // (16,256,256)
  float* hard = out + (size_t)BB * NQQ * DMODEL;     // (16,8192,256)

  float* qk = (float*)d_ws;                          // 256 KB
  float* MT = qk + 65536;                            // 256 KB
  unsigned* cnt  = (unsigned*)(MT + 65536);          // 256 B
  unsigned* listF = cnt + 64;                        // 512 KB
  unsigned short* qhf = (unsigned short*)(listF + CAPF);  // 128 KB
  unsigned char*  idxa = (unsigned char*)(qhf + 65536);   // 128 KB

  prep_kernel<<<2 * NQQ, 256, 0, stream>>>(q, wks, wvs, wfc, qk, MT, qhf, cnt);
  score_kernel<<<dim3(NN / TOK, BB), 256, 0, stream>>>(x, qhf, hard, idxa, cnt, listF);
  fullcheck_kernel<<<1024, 256, 0, stream>>>(x, qk, cnt, listF, hard, idxa);
  reduce_kernel<<<BB * 16, 512, 0, stream>>>(x, idxa, MT, out);
}

// Round 25
// 152.695 us; speedup vs baseline: 1.1597x; 1.1597x over previous
//
#include <hip/hip_runtime.h>

#define BB 16
#define NN 8192
#define DMODEL 256
#define DKK 64
#define DVV 64
#define NQQ 256
#define TOK 32
#define MARGIN 0.16f
#define CAPF 131072
#define FB 16

typedef __attribute__((ext_vector_type(8))) short bf16x8;
typedef __attribute__((ext_vector_type(4))) float f32x4;

__device__ __forceinline__ unsigned short hi_bf16(float v) {
  unsigned u = __float_as_uint(v);
  return (unsigned short)(((u + 0x7FFFu + ((u >> 16) & 1u)) & 0xFFFF0000u) >> 16);
}

// prep: qk = q @ w_ks (f32, for recheck), bf16 fragments qhf, MT = (w_fc @ w_vs)^T
__global__ __launch_bounds__(256) void prep_kernel(
    const float* __restrict__ q, const float* __restrict__ w_ks,
    const float* __restrict__ w_vs, const float* __restrict__ w_fc,
    float* __restrict__ qk, float* __restrict__ MT,
    unsigned short* __restrict__ qhf, unsigned* __restrict__ cnt) {
  __shared__ float sbuf[DKK];
  const int tid = threadIdx.x;
  const int blk = blockIdx.x;
  if (blk == 0 && tid < 64) cnt[tid] = 0u;
  if (blk < NQQ) {
    const int s = blk;
    if (tid < DKK) sbuf[tid] = q[s * DKK + tid];
    __syncthreads();
    float acc = 0.f;
#pragma unroll
    for (int k = 0; k < DKK; ++k) acc = fmaf(sbuf[k], w_ks[k * DMODEL + tid], acc);
    qk[s * DMODEL + tid] = acc;
    int d = tid;
    int kstep = d >> 5, kg = (d >> 3) & 3, jj = d & 7;
    int stile = s >> 4, s15 = s & 15;
    int e = (((kstep * 16 + stile) * 64) + (kg * 16 + s15)) * 8 + jj;
    qhf[e] = hi_bf16(acc);
  } else {
    const int dm = blk - NQQ;
    if (tid < DVV) sbuf[tid] = w_vs[tid * DMODEL + dm];
    __syncthreads();
    float acc = 0.f;
#pragma unroll
    for (int v = 0; v < DVV; ++v) acc = fmaf(w_fc[tid * DVV + v], sbuf[v], acc);
    MT[dm * DMODEL + tid] = acc;
  }
}

// one k-step: prefetch B for k+1, FENCE, then 8 MFMAs for k
#define KSTEP(kk, Bhc, Bhn, PRE)                                                        \
  {                                                                                     \
    if (PRE) {                                                                          \
      _Pragma("unroll")                                                                 \
      for (int j = 0; j < 4; ++j)                                                       \
        Bhn[j] = bh[(((kk) + 1) * 16 + w * 4 + j) * 64 + l];                            \
      __builtin_amdgcn_sched_barrier(0);                                                \
    }                                                                                   \
    _Pragma("unroll")                                                                   \
    for (int i = 0; i < 2; ++i) {                                                       \
      bf16x8 Ah = *(const bf16x8*)(&xs_h[(((kk) * 2 + i) * 64 + l) * 8]);               \
      _Pragma("unroll")                                                                 \
      for (int j = 0; j < 4; ++j)                                                       \
        acc[i][j] = __builtin_amdgcn_mfma_f32_16x16x32_bf16(Ah, Bhc[j], acc[i][j], 0, 0, 0); \
    }                                                                                   \
  }

// main (measured optimum 83 us): bf16 MFMA scores; lean argmax;
// flagged (band>=2) -> batched fullcheck; nontemporal one-hot; idx byte.
__global__ __launch_bounds__(256, 4) void score_kernel(
    const float* __restrict__ x, const unsigned short* __restrict__ qhf,
    float* __restrict__ hard, unsigned char* __restrict__ idxa,
    unsigned* __restrict__ cnt, unsigned* __restrict__ listF) {
  __shared__ unsigned short xs_h[8192];   // 16 KB
  __shared__ float rm1[4][TOK];
  __shared__ int   ri1[4][TOK];
  __shared__ int   rcnt[4][TOK];
  __shared__ float bm1[TOK];
  __shared__ int   idx_s[TOK];

  const int tid = threadIdx.x;
  const int w = tid >> 6;
  const int l = tid & 63;
  const int b = blockIdx.y;
  const int n0 = blockIdx.x * TOK;
  const float* xbase = x + ((size_t)b * NN + n0) * DMODEL;
  const float4* xb4 = (const float4*)xbase;

  // ---- stage x tile as bf16-hi fragments ----
  {
    const int tok = w * 8 + (l >> 3);
    const int r   = l & 7;
    const int kg  = r >> 1;
    const int j0  = (r & 1) * 4;
    const int i   = tok >> 4;
    const int t15 = tok & 15;
#pragma unroll
    for (int it = 0; it < 8; ++it) {
      int c4 = it * 8 + r;
      float4 v = xb4[tok * 64 + c4];
      int e = (((it * 2 + i) * 64) + (kg * 16 + t15)) * 8 + j0;
      ushort4 hh;
      hh.x = hi_bf16(v.x); hh.y = hi_bf16(v.y);
      hh.z = hi_bf16(v.z); hh.w = hi_bf16(v.w);
      *(ushort4*)(&xs_h[e]) = hh;
    }
  }

  const bf16x8* bh = (const bf16x8*)qhf;
  bf16x8 BhA[4], BhB[4];
#pragma unroll
  for (int j = 0; j < 4; ++j) BhA[j] = bh[(w * 4 + j) * 64 + l];
  __syncthreads();

  f32x4 acc[2][4];
#pragma unroll
  for (int i = 0; i < 2; ++i)
#pragma unroll
    for (int j = 0; j < 4; ++j) acc[i][j] = (f32x4){0.f, 0.f, 0.f, 0.f};

  KSTEP(0, BhA, BhB, true)
  KSTEP(1, BhB, BhA, true)
  KSTEP(2, BhA, BhB, true)
  KSTEP(3, BhB, BhA, true)
  KSTEP(4, BhA, BhB, true)
  KSTEP(5, BhB, BhA, true)
  KSTEP(6, BhA, BhB, true)
  KSTEP(7, BhB, BhA, false)

  const int s15 = l & 15, g4 = l >> 4;

  // ---- pass A: per-wave value-only max ----
#pragma unroll
  for (int i = 0; i < 2; ++i) {
#pragma unroll
    for (int rr = 0; rr < 4; ++rr) {
      float m = fmaxf(fmaxf(acc[i][0][rr], acc[i][1][rr]),
                      fmaxf(acc[i][2][rr], acc[i][3][rr]));
#pragma unroll
      for (int off = 1; off < 16; off <<= 1)
        m = fmaxf(m, __shfl_xor(m, off, 64));
      if (s15 == 0) rm1[w][i * 16 + g4 * 4 + rr] = m;
    }
  }
  __syncthreads();

  // ---- global max per token ----
  if (tid < TOK)
    bm1[tid] = fmaxf(fmaxf(rm1[0][tid], rm1[1][tid]),
                     fmaxf(rm1[2][tid], rm1[3][tid]));
  __syncthreads();

  // ---- pass B: first-index of gmax + band count ----
#pragma unroll
  for (int i = 0; i < 2; ++i) {
#pragma unroll
    for (int rr = 0; rr < 4; ++rr) {
      int t = i * 16 + g4 * 4 + rr;
      float gm = bm1[t];
      float thr = gm - MARGIN;
      int c = 0;
      int im = 1024;
#pragma unroll
      for (int j = 0; j < 4; ++j) {
        float v = acc[i][j][rr];
        c += (v >= thr) ? 1 : 0;
        int s = w * 64 + j * 16 + s15;
        if (v == gm && s < im) im = s;
      }
#pragma unroll
      for (int off = 1; off < 16; off <<= 1) {
        c += __shfl_xor(c, off, 64);
        int oim = __shfl_xor(im, off, 64);
        im = min(im, oim);
      }
      if (s15 == 0) { rcnt[w][t] = c; ri1[w][t] = im; }
    }
  }
  __syncthreads();

  // ---- final: i1 = min matching index; flag if band >= 2 ----
  if (tid < TOK) {
    int i1 = min(min(ri1[0][tid], ri1[1][tid]), min(ri1[2][tid], ri1[3][tid]));
    int band = rcnt[0][tid] + rcnt[1][tid] + rcnt[2][tid] + rcnt[3][tid];
    idx_s[tid] = i1;
    idxa[(size_t)b * NN + n0 + tid] = (unsigned char)i1;
    if (band >= 2) {
      unsigned pos = atomicAdd(cnt, 1u);
      if (pos < CAPF) listF[pos] = (unsigned)(b * NN + n0 + tid);
    }
  }
  __syncthreads();

  // ---- one-hot write: nontemporal ----
  f32x4* hbase = (f32x4*)(hard + ((size_t)b * NN + n0) * NQQ);
#pragma unroll
  for (int it = 0; it < 8; ++it) {
    int u = it * 256 + tid;
    int tk = u >> 6;
    int s0 = (u & 63) * 4;
    int tgt = idx_s[tk];
    f32x4 h;
    h[0] = (s0 + 0 == tgt) ? 1.f : 0.f;
    h[1] = (s0 + 1 == tgt) ? 1.f : 0.f;
    h[2] = (s0 + 2 == tgt) ? 1.f : 0.f;
    h[3] = (s0 + 3 == tgt) ? 1.f : 0.f;
    __builtin_nontemporal_store(h, &hbase[u]);
  }
}

// full recheck: batched FB=16 tokens per block-iter; one qk sweep shared by all FB.
// Grid 2048 so ~1900 batches run 1 per block.
__global__ __launch_bounds__(256) void fullcheck_kernel(
    const float* __restrict__ x, const float* __restrict__ qk,
    const unsigned* __restrict__ cnt, const unsigned* __restrict__ listF,
    float* __restrict__ hard, unsigned char* __restrict__ idxa) {
  __shared__ float xs[FB][DMODEL];   // 16 KB
  __shared__ float sco[FB][NQQ];     // 16 KB
  __shared__ int   toks[FB];
  const int tid = threadIdx.x;
  unsigned n = cnt[0]; if (n > (unsigned)CAPF) n = CAPF;
  int nb = ((int)n + FB - 1) / FB;
  for (int batch = blockIdx.x; batch < nb; batch += gridDim.x) {
    int base = batch * FB;
    if (tid < FB) {
      int ei = base + tid;
      if (ei >= (int)n) ei = base;     // pad: duplicate first entry (idempotent)
      toks[tid] = (int)listF[ei];
    }
    __syncthreads();
#pragma unroll
    for (int t = 0; t < FB; ++t) xs[t][tid] = x[(size_t)toks[t] * DMODEL + tid];
    __syncthreads();
    float accv[FB];
#pragma unroll
    for (int t = 0; t < FB; ++t) accv[t] = 0.f;
    const float4* qrow = (const float4*)(qk + (size_t)tid * DMODEL);
    for (int d4 = 0; d4 < 64; ++d4) {
      float4 qv = qrow[d4];
#pragma unroll
      for (int t = 0; t < FB; ++t) {
        float4 xv = *(const float4*)(&xs[t][d4 * 4]);
        accv[t] = fmaf(qv.x, xv.x, accv[t]);
        accv[t] = fmaf(qv.y, xv.y, accv[t]);
        accv[t] = fmaf(qv.z, xv.z, accv[t]);
        accv[t] = fmaf(qv.w, xv.w, accv[t]);
      }
    }
#pragma unroll
    for (int t = 0; t < FB; ++t) sco[t][tid] = accv[t];
    __syncthreads();
    {
      int g = tid >> 4, j = tid & 15;
      float bv = -1e30f; int bs = 256;
#pragma unroll
      for (int k = 0; k < 16; ++k) {
        int s = j + k * 16;
        float v = sco[g][s];
        if (v > bv) { bv = v; bs = s; }
      }
#pragma unroll
      for (int off = 1; off < 16; off <<= 1) {
        float ov = __shfl_xor(bv, off, 64);
        int   os = __shfl_xor(bs, off, 64);
        if (ov > bv || (ov == bv && os < bs)) { bv = ov; bs = os; }
      }
      if (j == 0) {
        int tok = toks[g];
        int olds = (int)idxa[tok];
        if (bs != olds) {
          hard[(size_t)tok * NQQ + olds] = 0.f;
          hard[(size_t)tok * NQQ + bs] = 1.f;
          idxa[tok] = (unsigned char)bs;
        }
      }
    }
    __syncthreads();
  }
}

// reduce+out fused: ballot-compaction + 8-wide MLP batching; S never touches HBM.
__global__ __launch_bounds__(512) void reduce_kernel(
    const float* __restrict__ x, const unsigned char* __restrict__ idxa,
    const float* __restrict__ MT, float* __restrict__ out) {
  __shared__ unsigned char  idx_l[NN];
  __shared__ unsigned short list_l[NN];
  __shared__ float accs[2][16][DMODEL];
  __shared__ unsigned lcnt;
  const int tid = threadIdx.x;
  const int l   = tid & 63;
  const int b  = blockIdx.x >> 4;
  const int sg = blockIdx.x & 15;
  const int h  = tid >> 8;
  const int d  = tid & 255;

  uint4 myidx = ((const uint4*)(idxa + (size_t)b * NN))[tid];
  ((uint4*)idx_l)[tid] = myidx;
  float* af = &accs[0][0][0];
#pragma unroll
  for (int i = 0; i < 16; ++i) af[i * 512 + tid] = 0.f;
  if (tid == 0) lcnt = 0u;
  __syncthreads();

  // phase 1: ballot-compaction of matching token ids
  {
    unsigned base16 = (unsigned)tid * 16u;
    unsigned words[4] = {myidx.x, myidx.y, myidx.z, myidx.w};
    unsigned long long lanelo = (1ull << l) - 1ull;
#pragma unroll
    for (int wi = 0; wi < 4; ++wi)
#pragma unroll
      for (int j = 0; j < 4; ++j) {
        int s = (words[wi] >> (8 * j)) & 255;
        bool m = ((s >> 4) == sg);
        unsigned long long mask = __ballot(m);
        int cw = __popcll(mask);
        unsigned wbase = 0;
        if (l == 0 && cw) wbase = atomicAdd(&lcnt, (unsigned)cw);
        wbase = (unsigned)__shfl((int)wbase, 0, 64);
        if (m) {
          int pos = (int)wbase + __popcll(mask & lanelo);
          list_l[pos] = (unsigned short)(base16 + wi * 4 + j);
        }
      }
  }
  __syncthreads();

  // phase 2: accumulate matching rows (8-wide independent-load batching)
  const int cnt_ = (int)lcnt;
  const float* xb = x + (size_t)b * NN * DMODEL + d;
  float* myacc = &accs[h][0][0] + d;
  int start = (h * cnt_) >> 1;
  int end   = ((h + 1) * cnt_) >> 1;
  int i = start;
  for (; i + 8 <= end; i += 8) {
    int n0_ = list_l[i],     n1_ = list_l[i + 1];
    int n2_ = list_l[i + 2], n3_ = list_l[i + 3];
    int n4_ = list_l[i + 4], n5_ = list_l[i + 5];
    int n6_ = list_l[i + 6], n7_ = list_l[i + 7];
    float v0 = xb[(size_t)n0_ * DMODEL];
    float v1 = xb[(size_t)n1_ * DMODEL];
    float v2 = xb[(size_t)n2_ * DMODEL];
    float v3 = xb[(size_t)n3_ * DMODEL];
    float v4 = xb[(size_t)n4_ * DMODEL];
    float v5 = xb[(size_t)n5_ * DMODEL];
    float v6 = xb[(size_t)n6_ * DMODEL];
    float v7 = xb[(size_t)n7_ * DMODEL];
    myacc[(idx_l[n0_] & 15) * DMODEL] += v0;
    myacc[(idx_l[n1_] & 15) * DMODEL] += v1;
    myacc[(idx_l[n2_] & 15) * DMODEL] += v2;
    myacc[(idx_l[n3_] & 15) * DMODEL] += v3;
    myacc[(idx_l[n4_] & 15) * DMODEL] += v4;
    myacc[(idx_l[n5_] & 15) * DMODEL] += v5;
    myacc[(idx_l[n6_] & 15) * DMODEL] += v6;
    myacc[(idx_l[n7_] & 15) * DMODEL] += v7;
  }
  for (; i < end; ++i) {
    int nn = list_l[i];
    myacc[(idx_l[nn] & 15) * DMODEL] += xb[(size_t)nn * DMODEL];
  }
  __syncthreads();

  // combine halves: accs[0] += accs[1]
#pragma unroll
  for (int ii = 0; ii < 8; ++ii) {
    int u = ii * 512 + tid;
    accs[0][u >> 8][u & 255] += accs[1][u >> 8][u & 255];
  }
  __syncthreads();

  // fused out: rows ss = h*8 .. h*8+7 of this slot-group
  float a[8];
#pragma unroll
  for (int i2 = 0; i2 < 8; ++i2) a[i2] = 0.f;
  for (int dm = 0; dm < DMODEL; ++dm) {
    float m = MT[(size_t)dm * DMODEL + d];
#pragma unroll
    for (int i2 = 0; i2 < 8; ++i2)
      a[i2] = fmaf(accs[0][h * 8 + i2][dm], m, a[i2]);
  }
  float* ob = out + ((size_t)b * NQQ + sg * 16 + h * 8) * DMODEL + d;
#pragma unroll
  for (int i2 = 0; i2 < 8; ++i2) ob[(size_t)i2 * DMODEL] = a[i2];
}

extern "C" void kernel_launch(void* const* d_in, const int* in_sizes, int n_in,
                              void* d_out, int out_size, void* d_ws, size_t ws_size,
                              hipStream_t stream) {
  const float* x   = (const float*)d_in[0];
  const float* q   = (const float*)d_in[1];
  const float* wks = (const float*)d_in[2];
  const float* wvs = (const float*)d_in[3];
  const float* wfc = (const float*)d_in[4];

  float* out  = (float*)d_out;                       // (16,256,256)
  float* hard = out + (size_t)BB * NQQ * DMODEL;     // (16,8192,256)

  float* qk = (float*)d_ws;                          // 256 KB
  float* MT = qk + 65536;                            // 256 KB
  unsigned* cnt  = (unsigned*)(MT + 65536);          // 256 B
  unsigned* listF = cnt + 64;                        // 512 KB
  unsigned short* qhf = (unsigned short*)(listF + CAPF);  // 128 KB
  unsigned char*  idxa = (unsigned char*)(qhf + 65536);   // 128 KB

  prep_kernel<<<2 * NQQ, 256, 0, stream>>>(q, wks, wvs, wfc, qk, MT, qhf, cnt);
  score_kernel<<<dim3(NN / TOK, BB), 256, 0, stream>>>(x, qhf, hard, idxa, cnt, listF);
  fullcheck_kernel<<<2048, 256, 0, stream>>>(x, qk, cnt, listF, hard, idxa);
  reduce_kernel<<<BB * 16, 512, 0, stream>>>(x, idxa, MT, out);
}